// Round 1
// 263.697 us; speedup vs baseline: 1.0135x; 1.0135x over previous
//
#include <hip/hip_runtime.h>
#include <stdint.h>

// TopoSignature via parallel Boruvka MST. Round 12: r11 structure (267 us)
// with MLP-batched scans.
//  - scanA: VGPR_Count was 12 -> compiler serialized the 16 row loads
//    (load->wait->umin chain, ~2 outstanding). Counters: VALUBusy 18%,
//    occupancy 65%, eff. BW 3.0 TB/s of 6.3 -> latency-bound, NOT a pattern
//    ceiling. Fix: batch 8 float4 loads into named regs before processing
//    (~50 VGPR, under the 64 cap of launch_bounds(256,8)), and split the
//    64-deep umin64 chain into 4 accumulators (assoc. min, unique keys ->
//    bit-identical result).
//  - scan2 need-path / scanF: same serialization, batched 4-deep.
// Lessons kept: kernel boundary = the only cheap device-wide barrier (r8:
// threadfence ticket ~50-270us/round; r10: replicated hook = 94 MB re-reads
// + 7.5M LDS conflicts). init folded in scanA; epilogue fused in final hook.

#define N        4096
#define NROUNDS  12

typedef unsigned long long u64;
typedef uint32_t u32;

#define INFK (~0ull)

struct Ws {
    u64 best[2][N];      // per-component min outgoing edge key: (wbits<<24)|(lo<<12)|hi
    u32 comp[2][N];      // vertex -> component root label
    u32 edges[2][N];     // edge slot per vertex, (lo<<12)|hi; (i<<12)|i = none
    u32 ncomp[2];
    u32 pad[14];
    u64 bm[2][N * 64];   // per-row per-lane-block bound keys: (wbits<<12)|col ; 4 MB
};

__device__ __forceinline__ u64 umin64(u64 a, u64 b) { return a < b ? a : b; }

__device__ __forceinline__ u64 shfl_xor_u64(u64 x, int off) {
    u32 lo = (u32)x, hi = (u32)(x >> 32);
    lo = (u32)__shfl_xor((int)lo, off, 64);
    hi = (u32)__shfl_xor((int)hi, off, 64);
    return ((u64)hi << 32) | lo;
}

// ---- round 1 full scan + state init. One wave per row; lane-private block
// minima (block L = cols ≡ [4L,4L+4) mod 256). 8-deep load batches for MLP. ----
__launch_bounds__(256, 8)
__global__ void scanA_k(const float* __restrict__ d1, const float* __restrict__ d2,
                        Ws* __restrict__ ws) {
    const int m = blockIdx.x >> 10;
    const int wave = threadIdx.x >> 6, lane = threadIdx.x & 63;
    const int v = ((blockIdx.x & 1023) << 2) + wave;
    const float4* __restrict__ row4 = (const float4*)((m ? d2 : d1) + (size_t)v * N);

    const u32 uv = (u32)v;
    // 4 independent accumulators (x/y/z/w) -> dep chain 16 deep, not 64.
    u64 a0 = INFK, a1 = INFK, a2 = INFK, a3 = INFK;
    #pragma unroll
    for (int half = 0; half < 2; ++half) {
        float4 w[8];
        #pragma unroll
        for (int j = 0; j < 8; ++j)
            w[j] = row4[lane + 64 * (8 * half + j)];
        #pragma unroll
        for (int j = 0; j < 8; ++j) {
            const u32 c0 = (u32)(4 * (lane + 64 * (8 * half + j)));
            if (c0 + 0 != uv) a0 = umin64(a0, (((u64)__float_as_uint(w[j].x)) << 12) | (c0 + 0));
            if (c0 + 1 != uv) a1 = umin64(a1, (((u64)__float_as_uint(w[j].y)) << 12) | (c0 + 1));
            if (c0 + 2 != uv) a2 = umin64(a2, (((u64)__float_as_uint(w[j].z)) << 12) | (c0 + 2));
            if (c0 + 3 != uv) a3 = umin64(a3, (((u64)__float_as_uint(w[j].w)) << 12) | (c0 + 3));
        }
    }
    u64 bmin = umin64(umin64(a0, a1), umin64(a2, a3));
    ws->bm[m][(size_t)v * 64 + lane] = bmin;      // coalesced 512 B store

    u64 rowmin = bmin;
    #pragma unroll
    for (int off = 1; off <= 32; off <<= 1)
        rowmin = umin64(rowmin, shfl_xor_u64(rowmin, off));

    if (lane == 0) {
        u32 u  = (u32)rowmin & 0xFFFu;
        u64 wb = rowmin >> 12;
        u32 lo = min(uv, u), hi = max(uv, u);
        ws->best[m][v]  = (wb << 24) | ((u64)lo << 12) | (u64)hi;  // comp==v, unique writer
        ws->comp[m][v]  = uv;                                       // init fold
        ws->edges[m][v] = (uv << 12) | uv;                          // diag sentinel
    }
    if (threadIdx.x == 0 && (blockIdx.x & 1023) == 0)
        ws->ncomp[m] = (u32)N;
}

// ---- rounds 2+: bound-table scan. One wave per row, lane = block. ----
__launch_bounds__(256, 8)
__global__ void scan2_k(const float* __restrict__ d1, const float* __restrict__ d2,
                        Ws* __restrict__ ws) {
    const int m = blockIdx.x >> 10;
    if (ws->ncomp[m] <= 1u) return;
    const int wave = threadIdx.x >> 6, lane = threadIdx.x & 63;
    const int v = ((blockIdx.x & 1023) << 2) + wave;

    const float* __restrict__ dm = m ? d2 : d1;
    const u32*   __restrict__ cm = ws->comp[m];
    u64* __restrict__ bmrow = ws->bm[m] + (size_t)v * 64;

    const u32 cv = cm[v];
    u64 key = bmrow[lane];
    bool cross = false;
    if (key != INFK) cross = (cm[(u32)key & 0xFFFu] != cv);

    // best cross candidate among stored block mins (exact entries)
    u64 kb = cross ? key : INFK;
    #pragma unroll
    for (int off = 1; off <= 32; off <<= 1)
        kb = umin64(kb, shfl_xor_u64(kb, off));

    // intra bound undercutting kb -> block may hide a smaller cross entry
    const bool need = (!cross) && (key < kb);
    u64 nm = INFK;
    if (need) {
        const float4* __restrict__ row4 = (const float4*)(dm + (size_t)v * N);
        const uint4*  __restrict__ c4   = (const uint4*)cm;
        u64 n0 = INFK, n1 = INFK, n2 = INFK, n3 = INFK;
        #pragma unroll
        for (int q = 0; q < 4; ++q) {
            float4 w[4];
            uint4  cu[4];
            #pragma unroll
            for (int j = 0; j < 4; ++j) {
                const int c = lane + 64 * (4 * q + j);
                w[j]  = row4[c];
                cu[j] = c4[c];
            }
            #pragma unroll
            for (int j = 0; j < 4; ++j) {
                const u32 c0 = (u32)(4 * (lane + 64 * (4 * q + j)));
                if (cu[j].x != cv) n0 = umin64(n0, (((u64)__float_as_uint(w[j].x)) << 12) | (c0 + 0));
                if (cu[j].y != cv) n1 = umin64(n1, (((u64)__float_as_uint(w[j].y)) << 12) | (c0 + 1));
                if (cu[j].z != cv) n2 = umin64(n2, (((u64)__float_as_uint(w[j].z)) << 12) | (c0 + 2));
                if (cu[j].w != cv) n3 = umin64(n3, (((u64)__float_as_uint(w[j].w)) << 12) | (c0 + 3));
            }
        }
        nm = umin64(umin64(n0, n1), umin64(n2, n3));
        bmrow[lane] = nm;    // tightened bound: block's current min-cross key
    }
    u64 kb2 = need ? nm : INFK;
    #pragma unroll
    for (int off = 1; off <= 32; off <<= 1)
        kb2 = umin64(kb2, shfl_xor_u64(kb2, off));

    u64 fin = umin64(kb, kb2);
    if (lane == 0 && fin != INFK) {
        u32 u  = (u32)fin & 0xFFFu;
        u64 wb = fin >> 12;
        u32 lo = min((u32)v, u), hi = max((u32)v, u);
        u64 g  = (wb << 24) | ((u64)lo << 12) | (u64)hi;
        if (g < ws->best[m][cv])
            atomicMin(&ws->best[m][cv], g);
    }
}

// ---- fallback full scan (ws too small for bound table) ----
__launch_bounds__(256, 8)
__global__ void scanF_k(const float* __restrict__ d1, const float* __restrict__ d2,
                        Ws* __restrict__ ws, int first) {
    const int m = blockIdx.x >> 10;
    if (!first && ws->ncomp[m] <= 1u) return;
    const int wave = threadIdx.x >> 6, lane = threadIdx.x & 63;
    const int v = ((blockIdx.x & 1023) << 2) + wave;
    const float* __restrict__ dm = m ? d2 : d1;
    const u32*   __restrict__ cm = ws->comp[m];
    const float4* __restrict__ row4 = (const float4*)(dm + (size_t)v * N);
    const uint4*  __restrict__ c4   = (const uint4*)cm;
    const u32 cv = first ? (u32)v : cm[v];
    u64 k0 = INFK, k1 = INFK, k2 = INFK, k3 = INFK;
    #pragma unroll
    for (int q = 0; q < 4; ++q) {
        float4 w[4];
        uint4  cu[4];
        #pragma unroll
        for (int j = 0; j < 4; ++j) {
            const int c = lane + 64 * (4 * q + j);
            w[j] = row4[c];
            if (!first) cu[j] = c4[c];
        }
        #pragma unroll
        for (int j = 0; j < 4; ++j) {
            const u32 c0 = (u32)(4 * (lane + 64 * (4 * q + j)));
            bool x0, x1, x2, x3;
            if (first) {
                x0 = (c0+0 != cv); x1 = (c0+1 != cv); x2 = (c0+2 != cv); x3 = (c0+3 != cv);
            } else {
                x0 = (cu[j].x != cv); x1 = (cu[j].y != cv); x2 = (cu[j].z != cv); x3 = (cu[j].w != cv);
            }
            if (x0) k0 = umin64(k0, (((u64)__float_as_uint(w[j].x)) << 12) | (c0 + 0));
            if (x1) k1 = umin64(k1, (((u64)__float_as_uint(w[j].y)) << 12) | (c0 + 1));
            if (x2) k2 = umin64(k2, (((u64)__float_as_uint(w[j].z)) << 12) | (c0 + 2));
            if (x3) k3 = umin64(k3, (((u64)__float_as_uint(w[j].w)) << 12) | (c0 + 3));
        }
    }
    u64 kmin = umin64(umin64(k0, k1), umin64(k2, k3));
    #pragma unroll
    for (int off = 1; off <= 32; off <<= 1)
        kmin = umin64(kmin, shfl_xor_u64(kmin, off));
    if (lane == 0 && kmin != INFK) {
        u32 u  = (u32)kmin & 0xFFFu;
        u64 wb = kmin >> 12;
        u32 lo = min((u32)v, u), hi = max((u32)v, u);
        u64 g  = (wb << 24) | ((u64)lo << 12) | (u64)hi;
        if (first) {
            ws->best[m][v]  = g;
            ws->comp[m][v]  = (u32)v;
            ws->edges[m][v] = ((u32)v << 12) | (u32)v;
        } else if (g < ws->best[m][cv]) {
            atomicMin(&ws->best[m][cv], g);
        }
    }
    if (first && threadIdx.x == 0 && (blockIdx.x & 1023) == 0)
        ws->ncomp[m] = (u32)N;
}

// ---- hook: resolve 2-cycles, record edges (slot = dying root id),
// pointer-jump (early exit), relabel, reset best. One 1024-thread block per
// matrix. fin: also run the fused epilogue (even on the dead path). ----
__launch_bounds__(1024, 1)
__global__ void hook_k(const float* __restrict__ d1, const float* __restrict__ d2,
                       Ws* __restrict__ ws, float* __restrict__ out, int fin) {
    const int m = blockIdx.x;
    const int tid = threadIdx.x;
    const int lane = tid & 63, wave = tid >> 6;

    __shared__ u32 compL[N];
    __shared__ u32 nxtA[N];
    __shared__ u32 nxtB[N];
    __shared__ u32 red[16];
    __shared__ float fpart[16];

    if (ws->ncomp[m] > 1u) {
        u32* __restrict__ gcomp = ws->comp[m];
        u64* __restrict__ best  = ws->best[m];

        {
            uint4* dst = (uint4*)compL;
            const uint4* src = (const uint4*)gcomp;
            if (tid < N / 4) dst[tid] = src[tid];
        }
        __syncthreads();

        bool isroot[4];
        u64  bkey[4];

        #pragma unroll
        for (int k = 0; k < 4; ++k) {
            int i = tid + k * 1024;
            u32 x = (u32)i;
            bool r = (compL[i] == (u32)i);
            isroot[k] = r;
            u64 g = 0;
            if (r) {
                g = best[i];
                u32 lo = (u32)(g >> 12) & 0xFFFu;
                u32 hi = (u32)g & 0xFFFu;
                u32 cl = compL[lo], ch = compL[hi];
                x = (cl == (u32)i) ? ch : cl;
            }
            bkey[k] = g;
            nxtA[i] = x;
        }
        __syncthreads();

        #pragma unroll
        for (int k = 0; k < 4; ++k) {
            int i = tid + k * 1024;
            u32 nn = (u32)i;
            if (isroot[k]) {
                u32 o = nxtA[i];
                bool mutual = (nxtA[o] == (u32)i);
                nn = (mutual && ((u32)i < o)) ? (u32)i : o;
                if (nn != (u32)i)
                    ws->edges[m][i] = (u32)(bkey[k] & 0xFFFFFFu);
            }
            nxtB[i] = nn;
        }
        __syncthreads();

        // pointer jumping with early exit (typical depth <= 4)
        for (int s = 0; s < 12; ++s) {
            u32 changed = 0;
            #pragma unroll
            for (int k = 0; k < 4; ++k) {
                int i = tid + k * 1024;
                u32 a = nxtB[i];
                u32 t = nxtB[a];
                if (t != a) changed = 1u;
                nxtB[i] = t;
            }
            if (!__syncthreads_or((int)changed)) break;
        }

        u32 cnt = 0;
        #pragma unroll
        for (int k = 0; k < 4; ++k) {
            int i = tid + k * 1024;
            if (isroot[k] && nxtB[i] == (u32)i) cnt++;
        }
        #pragma unroll
        for (int off = 32; off >= 1; off >>= 1) cnt += (u32)__shfl_down((int)cnt, off, 64);
        if (lane == 0) red[wave] = cnt;
        __syncthreads();

        #pragma unroll
        for (int k = 0; k < 4; ++k) {
            int i = tid + k * 1024;
            gcomp[i] = nxtB[compL[i]];
            if (isroot[k]) best[i] = INFK;
        }
        if (tid == 0) {
            u32 t = 0;
            #pragma unroll
            for (int w = 0; w < 16; ++w) t += red[w];
            ws->ncomp[m] = t;
        }
    }

    // ---- fused epilogue on the final round ----
    if (fin) {
        __syncthreads();
        float acc = 0.f;
        #pragma unroll
        for (int k = 0; k < 4; ++k) {
            int i = tid + k * 1024;
            u32 pk = ws->edges[m][i];
            u32 lo = (pk >> 12) & 0xFFFu, hi = pk & 0xFFFu;
            size_t off = (size_t)lo * N + hi;
            float df = d1[off] - d2[off];     // diagonal sentinel -> 0
            acc += df * df;
        }
        #pragma unroll
        for (int off = 32; off >= 1; off >>= 1) acc += __shfl_down(acc, off, 64);
        if (lane == 0) fpart[wave] = acc;
        __syncthreads();
        if (tid == 0) {
            float t = 0.f;
            #pragma unroll
            for (int w = 0; w < 16; ++w) t += fpart[w];
            atomicAdd(out, t);
        }
    }
}

extern "C" void kernel_launch(void* const* d_in, const int* in_sizes, int n_in,
                              void* d_out, int out_size, void* d_ws, size_t ws_size,
                              hipStream_t stream) {
    (void)in_sizes; (void)n_in; (void)out_size;
    const float* d1 = (const float*)d_in[0];
    const float* d2 = (const float*)d_in[1];
    float* out = (float*)d_out;
    Ws* ws = (Ws*)d_ws;
    const bool big = (ws_size >= sizeof(Ws));   // ~4.4 MB needed for bound table

    hipMemsetAsync(d_out, 0, sizeof(float), stream);
    for (int r = 0; r < NROUNDS; ++r) {
        if (big) {
            if (r == 0) scanA_k<<<dim3(2048), dim3(256), 0, stream>>>(d1, d2, ws);
            else        scan2_k<<<dim3(2048), dim3(256), 0, stream>>>(d1, d2, ws);
        } else {
            scanF_k<<<dim3(2048), dim3(256), 0, stream>>>(d1, d2, ws, r == 0 ? 1 : 0);
        }
        hook_k<<<dim3(2), dim3(1024), 0, stream>>>(d1, d2, ws, out, r == NROUNDS - 1 ? 1 : 0);
    }
}